// Round 4
// baseline (450.252 us; speedup 1.0000x reference)
//
#include <hip/hip_runtime.h>
#include <hip/hip_bf16.h>

// out[b,s,o] = sum_k x[b,s,k] * W[o,k] + bias[o],  W[o,k] = sum_d codebook[idx[o,d]] * rot[k,d]
// bf16 path: dequant+convert, GEMM1 (W = Wr @ R^T, bf16 out), GEMM2 (out = X @ W^T + bias, f32).
// GEMM: 256x256 tile, BK=64, 8 waves (2Mx4N), 4-phase/K-tile schedule, T+2-deep prefetch with
// counted vmcnt(8) (T3+T4), LDS XOR-swizzle (T2), setprio (T5), XCD-aware block swizzle (T1).
// RACE FIX (R3 post-mortem): fragment reads interleave across BOTH 128-row regions of an
// operand (ldA row = wr*128+mh*64+..., ldB row = wc*64+nh*32+...), so a region is only safe to
// stage after ALL phases reading that OPERAND have drained: B's last reader is phase 1 ->
// stage B(T+2) in phase 2; A's last reader is phase 2 -> stage A(T+2) in phase 3.

typedef __attribute__((ext_vector_type(8))) __bf16 bf16x8;
typedef __attribute__((ext_vector_type(4))) float f32x4;

#define GLOAD_LDS16(g, l)                                                        \
  __builtin_amdgcn_global_load_lds((__attribute__((address_space(1))) void*)(g), \
                                   (__attribute__((address_space(3))) void*)(l), \
                                   16, 0, 0)

// ---------------- conversion kernels ----------------

__global__ __launch_bounds__(256) void cvt_f32_bf16(const float* __restrict__ in,
                                                    __hip_bfloat16* __restrict__ out, int n4) {
  int i = blockIdx.x * 256 + threadIdx.x;
  if (i >= n4) return;
  float4 v = *(const float4*)(in + (size_t)i * 4);
  union { __hip_bfloat16 h[4]; ushort4 u; } o;
  o.h[0] = __float2bfloat16(v.x);
  o.h[1] = __float2bfloat16(v.y);
  o.h[2] = __float2bfloat16(v.z);
  o.h[3] = __float2bfloat16(v.w);
  *(ushort4*)((unsigned short*)out + (size_t)i * 4) = o.u;
}

__global__ __launch_bounds__(256) void dequant_bf16(const int* __restrict__ idx,
                                                    const float* __restrict__ cb,
                                                    __hip_bfloat16* __restrict__ out, int n4) {
  __shared__ __hip_bfloat16 scb[16];
  if (threadIdx.x < 16) scb[threadIdx.x] = __float2bfloat16(cb[threadIdx.x]);
  __syncthreads();
  int i = blockIdx.x * 256 + threadIdx.x;
  if (i >= n4) return;
  int4 v = *(const int4*)(idx + (size_t)i * 4);
  union { __hip_bfloat16 h[4]; ushort4 u; } o;
  o.h[0] = scb[v.x & 15];
  o.h[1] = scb[v.y & 15];
  o.h[2] = scb[v.z & 15];
  o.h[3] = scb[v.w & 15];
  *(ushort4*)((unsigned short*)out + (size_t)i * 4) = o.u;
}

// ---------------- 256^2 4-phase NT bf16 GEMM: C[M,N] = A[M,K] @ B[N,K]^T ----------------
// LDS: sA[2 dbuf][256][64] + sB[2 dbuf][256][64] bf16 = 128 KiB (static).
// Half-tile = 128 rows x 64 cols of A or B (16KB) = 2 global_load_lds issues/wave.
// Swizzle: physical_byte = row*128 + (col_byte ^ ((row&7)<<4)); write side realized by
// inverse-swizzling the per-lane GLOBAL source (gload_lds LDS dest must stay linear).
// Prefetch: during tile T stage tile T+2 into the buffer tile T is reading: B in phase 2,
// A in phase 3 (each after the operand's last reader drained). Boundary wait = vmcnt(8)
// (T+2's 8 loads stay in flight); loads blocked on were issued >= 4 phases earlier.

template <bool OUT_BF16>
__global__ __launch_bounds__(512, 2) void gemm256(const __hip_bfloat16* __restrict__ A,
                                                  const __hip_bfloat16* __restrict__ B,
                                                  void* __restrict__ Cv,
                                                  const float* __restrict__ bias,
                                                  int M, int N, int K) {
  __shared__ __align__(16) char smem[131072];

  const int nbn = N >> 8;
  const int nwg = (M >> 8) * nbn;
  const int bid0 = blockIdx.x;
  const int cpx = nwg >> 3;  // nwg % 8 == 0 for our shapes -> simple bijective XCD swizzle
  const int bid = (bid0 & 7) * cpx + (bid0 >> 3);
  const int m0 = (bid / nbn) << 8;
  const int n0 = (bid % nbn) << 8;

  const int tid = (int)threadIdx.x;
  const int lane = tid & 63;
  const int w = tid >> 6;   // wave 0..7
  const int wr = w >> 2;    // 0..1 -> 128 rows
  const int wc = w & 3;     // 0..3 -> 64 cols
  const int fr = lane & 15;
  const int fq = lane >> 4;

  // staging lane pattern: srow = row within 8-row stripe, scol = inverse-swizzled col
  const int srow = lane >> 3;                 // 0..7
  const int scol = ((lane & 7) ^ srow) << 3;  // element offset within 64-col row

  const __hip_bfloat16* Ab = A + (size_t)m0 * K;
  const __hip_bfloat16* Bb = B + (size_t)n0 * K;

  const int NT = K >> 6;

  f32x4 acc[8][4];
#pragma unroll
  for (int i = 0; i < 8; ++i)
#pragma unroll
    for (int j = 0; j < 4; ++j) acc[i][j] = (f32x4){0.f, 0.f, 0.f, 0.f};

  // stage half-tile s = 4*t + kind (kind: 0=A-half0, 1=A-half1, 2=B-half0, 3=B-half1)
  auto stage = [&](int s) {
    const int t = s >> 2, kind = s & 3;
    const __hip_bfloat16* g = (kind < 2) ? Ab : Bb;
    char* region = smem + ((kind < 2) ? 0 : 65536) + (t & 1) * 32768 + (kind & 1) * 16384;
    const int grow = (kind & 1) * 128 + w * 16 + srow;
    const int k0 = t << 6;
#pragma unroll
    for (int j = 0; j < 2; ++j)
      GLOAD_LDS16(g + (size_t)(grow + j * 8) * K + (k0 + scol), region + w * 2048 + j * 1024);
  };

  const int sw = (fr & 7) << 4;  // read-side swizzle XOR (row&7 == fr&7 for all frag rows)

  auto ldA = [&](int b, int mh, int mf, int kk) -> bf16x8 {
    const int row = wr * 128 + mh * 64 + mf * 16 + fr;
    const int byte = b * 32768 + row * 128 + ((kk * 64 + fq * 16) ^ sw);
    return *(const bf16x8*)(smem + byte);
  };
  auto ldB = [&](int b, int nh, int nf, int kk) -> bf16x8 {
    const int row = wc * 64 + nh * 32 + nf * 16 + fr;
    const int byte = 65536 + b * 32768 + row * 128 + ((kk * 64 + fq * 16) ^ sw);
    return *(const bf16x8*)(smem + byte);
  };

  // prologue: stage K-tiles 0 and 1 entirely (16 loads/wave); wait tile 0 landed (<=8 left)
#pragma unroll
  for (int s = 0; s < 8; ++s) stage(s);
  __builtin_amdgcn_sched_barrier(0);
  asm volatile("s_waitcnt vmcnt(8)" ::: "memory");
  __builtin_amdgcn_sched_barrier(0);
  __builtin_amdgcn_s_barrier();

  bf16x8 af[4][2], b0[2][2], b1[2][2];

  for (int T = 0; T < NT; ++T) {
    const int b = T & 1;
    const bool pf = (T + 2 < NT);
    // ---- phase 0: read A-half0 + B-half0; MFMA q(m0,n0); no stage
#pragma unroll
    for (int mf = 0; mf < 4; ++mf)
#pragma unroll
      for (int kk = 0; kk < 2; ++kk) af[mf][kk] = ldA(b, 0, mf, kk);
#pragma unroll
    for (int nf = 0; nf < 2; ++nf)
#pragma unroll
      for (int kk = 0; kk < 2; ++kk) b0[nf][kk] = ldB(b, 0, nf, kk);
    __builtin_amdgcn_s_barrier();
    asm volatile("s_waitcnt lgkmcnt(0)" ::: "memory");
    __builtin_amdgcn_sched_barrier(0);
    __builtin_amdgcn_s_setprio(1);
#pragma unroll
    for (int mf = 0; mf < 4; ++mf)
#pragma unroll
      for (int nf = 0; nf < 2; ++nf)
#pragma unroll
        for (int kk = 0; kk < 2; ++kk)
          acc[mf][nf] =
              __builtin_amdgcn_mfma_f32_16x16x32_bf16(af[mf][kk], b0[nf][kk], acc[mf][nf], 0, 0, 0);
    __builtin_amdgcn_s_setprio(0);
    __builtin_amdgcn_s_barrier();

    // ---- phase 1: read B-half1 (B's LAST reader); MFMA q(m0,n1); no stage
#pragma unroll
    for (int nf = 0; nf < 2; ++nf)
#pragma unroll
      for (int kk = 0; kk < 2; ++kk) b1[nf][kk] = ldB(b, 1, nf, kk);
    __builtin_amdgcn_s_barrier();
    asm volatile("s_waitcnt lgkmcnt(0)" ::: "memory");
    __builtin_amdgcn_sched_barrier(0);
    __builtin_amdgcn_s_setprio(1);
#pragma unroll
    for (int mf = 0; mf < 4; ++mf)
#pragma unroll
      for (int nf = 0; nf < 2; ++nf)
#pragma unroll
        for (int kk = 0; kk < 2; ++kk)
          acc[mf][2 + nf] = __builtin_amdgcn_mfma_f32_16x16x32_bf16(af[mf][kk], b1[nf][kk],
                                                                    acc[mf][2 + nf], 0, 0, 0);
    __builtin_amdgcn_s_setprio(0);
    __builtin_amdgcn_s_barrier();

    // ---- phase 2: read A-half1 (A's LAST reader); stage B0+B1 of T+2 (all B readers of
    //              buf b drained at phase-1 close barrier); MFMA q(m1,n1)
#pragma unroll
    for (int mf = 0; mf < 4; ++mf)
#pragma unroll
      for (int kk = 0; kk < 2; ++kk) af[mf][kk] = ldA(b, 1, mf, kk);
    if (pf) {
      stage(4 * (T + 2) + 2);
      stage(4 * (T + 2) + 3);
    }
    __builtin_amdgcn_s_barrier();
    asm volatile("s_waitcnt lgkmcnt(0)" ::: "memory");
    __builtin_amdgcn_sched_barrier(0);
    __builtin_amdgcn_s_setprio(1);
#pragma unroll
    for (int mf = 0; mf < 4; ++mf)
#pragma unroll
      for (int nf = 0; nf < 2; ++nf)
#pragma unroll
        for (int kk = 0; kk < 2; ++kk)
          acc[4 + mf][2 + nf] = __builtin_amdgcn_mfma_f32_16x16x32_bf16(
              af[mf][kk], b1[nf][kk], acc[4 + mf][2 + nf], 0, 0, 0);
    __builtin_amdgcn_s_setprio(0);
    __builtin_amdgcn_s_barrier();

    // ---- phase 3: no LDS reads (registers only); stage A0+A1 of T+2 (all A readers of
    //              buf b drained at phase-2 close barrier); MFMA q(m1,n0);
    //              counted boundary vmcnt (8 = T+2's loads stay in flight)
    if (pf) {
      stage(4 * (T + 2) + 0);
      stage(4 * (T + 2) + 1);
    }
    __builtin_amdgcn_s_barrier();
    __builtin_amdgcn_s_setprio(1);
#pragma unroll
    for (int mf = 0; mf < 4; ++mf)
#pragma unroll
      for (int nf = 0; nf < 2; ++nf)
#pragma unroll
        for (int kk = 0; kk < 2; ++kk)
          acc[4 + mf][nf] = __builtin_amdgcn_mfma_f32_16x16x32_bf16(af[mf][kk], b0[nf][kk],
                                                                    acc[4 + mf][nf], 0, 0, 0);
    __builtin_amdgcn_s_setprio(0);
    __builtin_amdgcn_sched_barrier(0);
    if (pf) {
      asm volatile("s_waitcnt vmcnt(8)" ::: "memory");
    } else if (T + 2 == NT) {
      asm volatile("s_waitcnt vmcnt(0)" ::: "memory");
    }
    __builtin_amdgcn_sched_barrier(0);
    __builtin_amdgcn_s_barrier();
  }

  // ---- epilogue: C/D layout col = lane&15 (n-side), row = fq*4 + v (m-side)
  if constexpr (OUT_BF16) {
    __hip_bfloat16* C = (__hip_bfloat16*)Cv;
#pragma unroll
    for (int mi = 0; mi < 8; ++mi)
#pragma unroll
      for (int ni = 0; ni < 4; ++ni) {
        const size_t row = (size_t)(m0 + wr * 128 + (mi >> 2) * 64 + (mi & 3) * 16 + fq * 4);
        const int col = n0 + wc * 64 + (ni >> 1) * 32 + (ni & 1) * 16 + fr;
#pragma unroll
        for (int v = 0; v < 4; ++v) C[(row + v) * N + col] = __float2bfloat16(acc[mi][ni][v]);
      }
  } else {
    float* C = (float*)Cv;
    float bv[4];
#pragma unroll
    for (int ni = 0; ni < 4; ++ni)
      bv[ni] = bias[n0 + wc * 64 + (ni >> 1) * 32 + (ni & 1) * 16 + fr];
#pragma unroll
    for (int mi = 0; mi < 8; ++mi)
#pragma unroll
      for (int ni = 0; ni < 4; ++ni) {
        const size_t row = (size_t)(m0 + wr * 128 + (mi >> 2) * 64 + (mi & 3) * 16 + fq * 4);
        const int col = n0 + wc * 64 + (ni >> 1) * 32 + (ni & 1) * 16 + fr;
#pragma unroll
        for (int v = 0; v < 4; ++v) C[(row + v) * N + col] = acc[mi][ni][v] + bv[ni];
      }
  }
}

// ---------------- launch ----------------

extern "C" void kernel_launch(void* const* d_in, const int* in_sizes, int n_in,
                              void* d_out, int out_size, void* d_ws, size_t ws_size,
                              hipStream_t stream) {
  const float* x = (const float*)d_in[0];        // [B,S,D] = [4,2048,4096] f32
  const int* indices = (const int*)d_in[1];      // [O,D] = [4096,4096] i32
  const float* codebook = (const float*)d_in[2]; // [16] f32
  const float* rot = (const float*)d_in[3];      // [K,D] = [4096,4096] f32
  const float* bias = (const float*)d_in[4];     // [O] f32
  float* out = (float*)d_out;                    // [B*S, O] f32

  const int D = 4096, O = 4096;
  const int M = in_sizes[0] / D;  // 8192

  char* ws = (char*)d_ws;
  __hip_bfloat16* Xb = (__hip_bfloat16*)ws;                          // 64MB: [M,D] bf16
  __hip_bfloat16* Rb = (__hip_bfloat16*)(ws + ((size_t)64 << 20));   // 32MB: [K,D] bf16
  __hip_bfloat16* Wr = (__hip_bfloat16*)(ws + ((size_t)96 << 20));   // 32MB: [O,D] bf16
  __hip_bfloat16* Wb = (__hip_bfloat16*)(ws + ((size_t)128 << 20));  // 32MB: [O,K] bf16

  cvt_f32_bf16<<<(M * D / 4 + 255) / 256, 256, 0, stream>>>(x, Xb, M * D / 4);
  cvt_f32_bf16<<<(4096 * 4096 / 4 + 255) / 256, 256, 0, stream>>>(rot, Rb, 4096 * 4096 / 4);
  dequant_bf16<<<(4096 * 4096 / 4 + 255) / 256, 256, 0, stream>>>(indices, codebook, Wr,
                                                                  4096 * 4096 / 4);

  // GEMM1: Wb[o,k] = sum_d Wr[o,d] * Rb[k,d]   (4096^3, bf16 out)
  gemm256<true><<<dim3((O / 256) * (4096 / 256)), 512, 0, stream>>>(Wr, Rb, Wb, nullptr, O, 4096,
                                                                    D);
  // GEMM2: out[m,o] = sum_k Xb[m,k] * Wb[o,k] + bias[o]   (8192x4096x4096, f32 out)
  gemm256<false><<<dim3((M / 256) * (O / 256)), 512, 0, stream>>>(Xb, Wb, out, bias, M, O, 4096);
}

// Round 5
// 441.215 us; speedup vs baseline: 1.0205x; 1.0205x over previous
//
#include <hip/hip_runtime.h>
#include <hip/hip_bf16.h>

// out[b,s,o] = sum_k x[b,s,k] * W[o,k] + bias[o],  W[o,k] = sum_d codebook[idx[o,d]] * rot[k,d]
// bf16 path: dequant+convert, GEMM1 (W = Wr @ R^T, bf16 out), GEMM2 (out = X @ W^T + bias, f32).
// GEMM: 256x256 tile, BK=64, 8 waves (2Mx4N), 4 phases/K-tile decomposed by (m-half, k-half):
//   ph0: read A(m0,k0)+B(:,k0) [8 ds_read], stage A0(T+1), MFMA acc[0-3][:] k0
//   ph1: read A(m0,k1)+B(:,k1) [8],         stage A1(T+1), MFMA acc[0-3][:] k1
//   ph2: read A(m1,k0)          [4],         stage B0(T+2), MFMA acc[4-7][:] k0 (B k0 in regs)
//   ph3: read A(m1,k1)          [4],         stage B1(T+2), MFMA acc[4-7][:] k1
// -> uniform 1 half-tile stage per phase, reads 8/8/4/4 (m201-matching interleave),
//    boundary vmcnt(4) = B(T+2) in flight, youngest awaited load issued 2 phases earlier.
// Region-drain audit: A(T+1) targets buf^1 A-region, last read T-1.ph3 (barrier-closed);
// B(T+2) targets buf B-region, last read T.ph1 (barrier-closed). T2 LDS XOR-swizzle,
// T5 setprio, T1 XCD swizzle as before.

typedef __attribute__((ext_vector_type(8))) __bf16 bf16x8;
typedef __attribute__((ext_vector_type(4))) float f32x4;

#define GLOAD_LDS16(g, l)                                                        \
  __builtin_amdgcn_global_load_lds((__attribute__((address_space(1))) void*)(g), \
                                   (__attribute__((address_space(3))) void*)(l), \
                                   16, 0, 0)

// ---------------- conversion kernels ----------------

__global__ __launch_bounds__(256) void cvt_f32_bf16(const float* __restrict__ in,
                                                    __hip_bfloat16* __restrict__ out, int n4) {
  int i = blockIdx.x * 256 + threadIdx.x;
  if (i >= n4) return;
  float4 v = *(const float4*)(in + (size_t)i * 4);
  union { __hip_bfloat16 h[4]; ushort4 u; } o;
  o.h[0] = __float2bfloat16(v.x);
  o.h[1] = __float2bfloat16(v.y);
  o.h[2] = __float2bfloat16(v.z);
  o.h[3] = __float2bfloat16(v.w);
  *(ushort4*)((unsigned short*)out + (size_t)i * 4) = o.u;
}

__global__ __launch_bounds__(256) void dequant_bf16(const int* __restrict__ idx,
                                                    const float* __restrict__ cb,
                                                    __hip_bfloat16* __restrict__ out, int n4) {
  __shared__ __hip_bfloat16 scb[16];
  if (threadIdx.x < 16) scb[threadIdx.x] = __float2bfloat16(cb[threadIdx.x]);
  __syncthreads();
  int i = blockIdx.x * 256 + threadIdx.x;
  if (i >= n4) return;
  int4 v = *(const int4*)(idx + (size_t)i * 4);
  union { __hip_bfloat16 h[4]; ushort4 u; } o;
  o.h[0] = scb[v.x & 15];
  o.h[1] = scb[v.y & 15];
  o.h[2] = scb[v.z & 15];
  o.h[3] = scb[v.w & 15];
  *(ushort4*)((unsigned short*)out + (size_t)i * 4) = o.u;
}

// ---------------- 256^2 4-phase NT bf16 GEMM: C[M,N] = A[M,K] @ B[N,K]^T ----------------

template <bool OUT_BF16>
__global__ __launch_bounds__(512, 2) void gemm256(const __hip_bfloat16* __restrict__ A,
                                                  const __hip_bfloat16* __restrict__ B,
                                                  void* __restrict__ Cv,
                                                  const float* __restrict__ bias,
                                                  int M, int N, int K) {
  __shared__ __align__(16) char smem[131072];

  const int nbn = N >> 8;
  const int nwg = (M >> 8) * nbn;
  const int bid0 = blockIdx.x;
  const int cpx = nwg >> 3;  // nwg % 8 == 0 for our shapes -> simple bijective XCD swizzle
  const int bid = (bid0 & 7) * cpx + (bid0 >> 3);
  const int m0 = (bid / nbn) << 8;
  const int n0 = (bid % nbn) << 8;

  const int tid = (int)threadIdx.x;
  const int lane = tid & 63;
  const int w = tid >> 6;   // wave 0..7
  const int wr = w >> 2;    // 0..1 -> 128 rows
  const int wc = w & 3;     // 0..3 -> 64 cols
  const int fr = lane & 15;
  const int fq = lane >> 4;

  // staging lane pattern: srow = row within 8-row stripe, scol = inverse-swizzled col
  const int srow = lane >> 3;                 // 0..7
  const int scol = ((lane & 7) ^ srow) << 3;  // element offset within 64-col row

  const __hip_bfloat16* Ab = A + (size_t)m0 * K;
  const __hip_bfloat16* Bb = B + (size_t)n0 * K;

  const int NT = K >> 6;

  f32x4 acc[8][4];
#pragma unroll
  for (int i = 0; i < 8; ++i)
#pragma unroll
    for (int j = 0; j < 4; ++j) acc[i][j] = (f32x4){0.f, 0.f, 0.f, 0.f};

  // stage half-tile s = 4*t + kind (kind: 0=A-half0, 1=A-half1, 2=B-half0, 3=B-half1)
  auto stage = [&](int s) {
    const int t = s >> 2, kind = s & 3;
    const __hip_bfloat16* g = (kind < 2) ? Ab : Bb;
    char* region = smem + ((kind < 2) ? 0 : 65536) + (t & 1) * 32768 + (kind & 1) * 16384;
    const int grow = (kind & 1) * 128 + w * 16 + srow;
    const int k0 = t << 6;
#pragma unroll
    for (int j = 0; j < 2; ++j)
      GLOAD_LDS16(g + (size_t)(grow + j * 8) * K + (k0 + scol), region + w * 2048 + j * 1024);
  };

  const int sw = (fr & 7) << 4;  // read-side swizzle XOR (row&7 == fr&7 for all frag rows)

  auto ldA = [&](int b, int mh, int mf, int kk) -> bf16x8 {
    const int row = wr * 128 + mh * 64 + mf * 16 + fr;
    const int byte = b * 32768 + row * 128 + ((kk * 64 + fq * 16) ^ sw);
    return *(const bf16x8*)(smem + byte);
  };
  auto ldB = [&](int b, int nf, int kk) -> bf16x8 {
    const int row = wc * 64 + nf * 16 + fr;
    const int byte = 65536 + b * 32768 + row * 128 + ((kk * 64 + fq * 16) ^ sw);
    return *(const bf16x8*)(smem + byte);
  };

  // prologue: tile 0 fully (A0,A1,B0,B1) + B(1) (ph2/ph3 slots of tile -1); wait tile 0
  stage(0); stage(1); stage(2); stage(3);
  stage(6); stage(7);
  asm volatile("s_waitcnt vmcnt(4)" ::: "memory");
  __builtin_amdgcn_s_barrier();

  bf16x8 af0[4], af1[4], bfr[4][2];

  for (int T = 0; T < NT; ++T) {
    const int b = T & 1;
    const bool pf1 = (T + 1 < NT);
    const bool pf2 = (T + 2 < NT);

    // ---- phase 0: read A(m0,k0) + B(:,k0) [8 reads]; stage A0(T+1); MFMA acc[0-3][:] k0
#pragma unroll
    for (int mf = 0; mf < 4; ++mf) af0[mf] = ldA(b, 0, mf, 0);
#pragma unroll
    for (int nf = 0; nf < 4; ++nf) bfr[nf][0] = ldB(b, nf, 0);
    if (pf1) stage(4 * (T + 1) + 0);
    __builtin_amdgcn_s_barrier();
    asm volatile("s_waitcnt lgkmcnt(0)");
    __builtin_amdgcn_sched_barrier(0);
    __builtin_amdgcn_s_setprio(1);
#pragma unroll
    for (int nf = 0; nf < 4; ++nf)
#pragma unroll
      for (int mf = 0; mf < 4; ++mf)
        acc[mf][nf] =
            __builtin_amdgcn_mfma_f32_16x16x32_bf16(af0[mf], bfr[nf][0], acc[mf][nf], 0, 0, 0);
    __builtin_amdgcn_s_setprio(0);
    __builtin_amdgcn_s_barrier();

    // ---- phase 1: read A(m0,k1) + B(:,k1) [8 reads]; stage A1(T+1); MFMA acc[0-3][:] k1
#pragma unroll
    for (int mf = 0; mf < 4; ++mf) af1[mf] = ldA(b, 0, mf, 1);
#pragma unroll
    for (int nf = 0; nf < 4; ++nf) bfr[nf][1] = ldB(b, nf, 1);
    if (pf1) stage(4 * (T + 1) + 1);
    __builtin_amdgcn_s_barrier();
    asm volatile("s_waitcnt lgkmcnt(0)");
    __builtin_amdgcn_sched_barrier(0);
    __builtin_amdgcn_s_setprio(1);
#pragma unroll
    for (int nf = 0; nf < 4; ++nf)
#pragma unroll
      for (int mf = 0; mf < 4; ++mf)
        acc[mf][nf] =
            __builtin_amdgcn_mfma_f32_16x16x32_bf16(af1[mf], bfr[nf][1], acc[mf][nf], 0, 0, 0);
    __builtin_amdgcn_s_setprio(0);
    __builtin_amdgcn_s_barrier();

    // ---- phase 2: read A(m1,k0) [4 reads]; stage B0(T+2) (B buf-b drained at ph1 barrier);
    //              MFMA acc[4-7][:] k0 (bfr[:][0] held in regs)
#pragma unroll
    for (int mf = 0; mf < 4; ++mf) af0[mf] = ldA(b, 1, mf, 0);
    if (pf2) stage(4 * (T + 2) + 2);
    __builtin_amdgcn_s_barrier();
    asm volatile("s_waitcnt lgkmcnt(0)");
    __builtin_amdgcn_sched_barrier(0);
    __builtin_amdgcn_s_setprio(1);
#pragma unroll
    for (int nf = 0; nf < 4; ++nf)
#pragma unroll
      for (int mf = 0; mf < 4; ++mf)
        acc[4 + mf][nf] =
            __builtin_amdgcn_mfma_f32_16x16x32_bf16(af0[mf], bfr[nf][0], acc[4 + mf][nf], 0, 0, 0);
    __builtin_amdgcn_s_setprio(0);
    __builtin_amdgcn_s_barrier();

    // ---- phase 3: read A(m1,k1) [4 reads]; stage B1(T+2); MFMA acc[4-7][:] k1;
    //              boundary: counted vmcnt(4) (= B(T+2) loads stay in flight)
#pragma unroll
    for (int mf = 0; mf < 4; ++mf) af1[mf] = ldA(b, 1, mf, 1);
    if (pf2) stage(4 * (T + 2) + 3);
    __builtin_amdgcn_s_barrier();
    asm volatile("s_waitcnt lgkmcnt(0)");
    __builtin_amdgcn_sched_barrier(0);
    __builtin_amdgcn_s_setprio(1);
#pragma unroll
    for (int nf = 0; nf < 4; ++nf)
#pragma unroll
      for (int mf = 0; mf < 4; ++mf)
        acc[4 + mf][nf] =
            __builtin_amdgcn_mfma_f32_16x16x32_bf16(af1[mf], bfr[nf][1], acc[4 + mf][nf], 0, 0, 0);
    __builtin_amdgcn_s_setprio(0);
    if (pf2) {
      asm volatile("s_waitcnt vmcnt(4)" ::: "memory");
    } else if (T + 2 == NT) {
      asm volatile("s_waitcnt vmcnt(0)" ::: "memory");
    }
    __builtin_amdgcn_s_barrier();
  }

  // ---- epilogue: C/D layout col = lane&15 (n-side), row = fq*4 + v (m-side)
  if constexpr (OUT_BF16) {
    __hip_bfloat16* C = (__hip_bfloat16*)Cv;
#pragma unroll
    for (int mi = 0; mi < 8; ++mi)
#pragma unroll
      for (int ni = 0; ni < 4; ++ni) {
        const size_t row = (size_t)(m0 + wr * 128 + (mi >> 2) * 64 + (mi & 3) * 16 + fq * 4);
        const int col = n0 + wc * 64 + ni * 16 + fr;
#pragma unroll
        for (int v = 0; v < 4; ++v) C[(row + v) * N + col] = __float2bfloat16(acc[mi][ni][v]);
      }
  } else {
    float* C = (float*)Cv;
    float bv[4];
#pragma unroll
    for (int ni = 0; ni < 4; ++ni) bv[ni] = bias[n0 + wc * 64 + ni * 16 + fr];
#pragma unroll
    for (int mi = 0; mi < 8; ++mi)
#pragma unroll
      for (int ni = 0; ni < 4; ++ni) {
        const size_t row = (size_t)(m0 + wr * 128 + (mi >> 2) * 64 + (mi & 3) * 16 + fq * 4);
        const int col = n0 + wc * 64 + ni * 16 + fr;
#pragma unroll
        for (int v = 0; v < 4; ++v) C[(row + v) * N + col] = acc[mi][ni][v] + bv[ni];
      }
  }
}

// ---------------- launch ----------------

extern "C" void kernel_launch(void* const* d_in, const int* in_sizes, int n_in,
                              void* d_out, int out_size, void* d_ws, size_t ws_size,
                              hipStream_t stream) {
  const float* x = (const float*)d_in[0];        // [B,S,D] = [4,2048,4096] f32
  const int* indices = (const int*)d_in[1];      // [O,D] = [4096,4096] i32
  const float* codebook = (const float*)d_in[2]; // [16] f32
  const float* rot = (const float*)d_in[3];      // [K,D] = [4096,4096] f32
  const float* bias = (const float*)d_in[4];     // [O] f32
  float* out = (float*)d_out;                    // [B*S, O] f32

  const int D = 4096, O = 4096;
  const int M = in_sizes[0] / D;  // 8192

  char* ws = (char*)d_ws;
  __hip_bfloat16* Xb = (__hip_bfloat16*)ws;                          // 64MB: [M,D] bf16
  __hip_bfloat16* Rb = (__hip_bfloat16*)(ws + ((size_t)64 << 20));   // 32MB: [K,D] bf16
  __hip_bfloat16* Wr = (__hip_bfloat16*)(ws + ((size_t)96 << 20));   // 32MB: [O,D] bf16
  __hip_bfloat16* Wb = (__hip_bfloat16*)(ws + ((size_t)128 << 20));  // 32MB: [O,K] bf16

  cvt_f32_bf16<<<(M * D / 4 + 255) / 256, 256, 0, stream>>>(x, Xb, M * D / 4);
  cvt_f32_bf16<<<(4096 * 4096 / 4 + 255) / 256, 256, 0, stream>>>(rot, Rb, 4096 * 4096 / 4);
  dequant_bf16<<<(4096 * 4096 / 4 + 255) / 256, 256, 0, stream>>>(indices, codebook, Wr,
                                                                  4096 * 4096 / 4);

  // GEMM1: Wb[o,k] = sum_d Wr[o,d] * Rb[k,d]   (4096^3, bf16 out)
  gemm256<true><<<dim3((O / 256) * (4096 / 256)), 512, 0, stream>>>(Wr, Rb, Wb, nullptr, O, 4096,
                                                                    D);
  // GEMM2: out[m,o] = sum_k Xb[m,k] * Wb[o,k] + bias[o]   (8192x4096x4096, f32 out)
  gemm256<false><<<dim3((M / 256) * (O / 256)), 512, 0, stream>>>(Xb, Wb, out, bias, M, O, 4096);
}